// Round 5
// baseline (410.015 us; speedup 1.0000x reference)
//
#include <hip/hip_runtime.h>

#define N_NODES 50000
#define N_EDGES 800000
#define N_FEAT 128
#define N_HID 128
#define N_CLS 40
#define BN_EPS 1e-5f

#define SCAN_BLOCKS ((N_NODES + 255) / 256)  // 196

// ---------------------------------------------------------------------------
// K1: int degree histogram.
// ---------------------------------------------------------------------------
__global__ __launch_bounds__(256) void deg_kernel(const int* __restrict__ dst,
                                                  int* __restrict__ deg_i) {
    int e = blockIdx.x * 256 + threadIdx.x;
    if (e < N_EDGES) atomicAdd(&deg_i[dst[e]], 1);
}

// ---------------------------------------------------------------------------
// Scan A/B/C: row_ptr = exclusive scan of degrees.
// ---------------------------------------------------------------------------
__global__ __launch_bounds__(256) void scanA_kernel(const int* __restrict__ deg_i,
                                                    int* __restrict__ row_ptr,
                                                    int* __restrict__ blk_sum) {
    __shared__ int tmp[256];
    int t = threadIdx.x;
    int i = blockIdx.x * 256 + t;
    int v = (i < N_NODES) ? deg_i[i] : 0;
    tmp[t] = v;
    __syncthreads();
    for (int off = 1; off < 256; off <<= 1) {
        int a = (t >= off) ? tmp[t - off] : 0;
        __syncthreads();
        if (t >= off) tmp[t] += a;
        __syncthreads();
    }
    if (i < N_NODES) row_ptr[i] = tmp[t] - v;
    if (t == 255) blk_sum[blockIdx.x] = tmp[255];
}

__global__ __launch_bounds__(256) void scanB_kernel(const int* __restrict__ blk_sum,
                                                    int* __restrict__ blk_off) {
    __shared__ int tmp[256];
    int t = threadIdx.x;
    int v = (t < SCAN_BLOCKS) ? blk_sum[t] : 0;
    tmp[t] = v;
    __syncthreads();
    for (int off = 1; off < 256; off <<= 1) {
        int a = (t >= off) ? tmp[t - off] : 0;
        __syncthreads();
        if (t >= off) tmp[t] += a;
        __syncthreads();
    }
    if (t < SCAN_BLOCKS) blk_off[t] = tmp[t] - v;
}

__global__ __launch_bounds__(256) void scanC_kernel(int* __restrict__ row_ptr,
                                                    const int* __restrict__ blk_off) {
    int i = blockIdx.x * 256 + threadIdx.x;
    if (i < N_NODES) row_ptr[i] += blk_off[blockIdx.x];
    if (i == 0) row_ptr[N_NODES] = N_EDGES;
}

// ---------------------------------------------------------------------------
// CSR fill.
// ---------------------------------------------------------------------------
__global__ __launch_bounds__(256) void fill_kernel(const int* __restrict__ src,
                                                   const int* __restrict__ dst,
                                                   const int* __restrict__ row_ptr,
                                                   int* __restrict__ cursor,
                                                   int* __restrict__ csr_src) {
    int e = blockIdx.x * 256 + threadIdx.x;
    if (e >= N_EDGES) return;
    int d = dst[e];
    int pos = atomicAdd(&cursor[d], 1);
    csr_src[row_ptr[d] + pos] = src[e];
}

// ---------------------------------------------------------------------------
// Weight transpose to k-major:
//   WtA[k][n] 256x128: k<128 -> W1l[n][k]; else W1r[n][k-128]
//   WtB[k][n] 128x80 : n<40 -> W2l[n][k]; else W2r[n-40][k]
// ---------------------------------------------------------------------------
__global__ __launch_bounds__(256) void transposeW_kernel(
    const float* __restrict__ W1l, const float* __restrict__ W1r,
    const float* __restrict__ W2l, const float* __restrict__ W2r,
    float* __restrict__ WtA, float* __restrict__ WtB) {
    int i = blockIdx.x * 256 + threadIdx.x;
    if (i < 256 * 128) {
        int k = i >> 7, n = i & 127;
        WtA[i] = (k < 128) ? W1l[n * 128 + k] : W1r[n * 128 + (k - 128)];
    } else {
        int j = i - 256 * 128;
        if (j < 128 * 80) {
            int k = j / 80, n = j % 80;
            WtB[j] = (n < 40) ? W2l[n * 128 + k] : W2r[(n - 40) * 128 + k];
        }
    }
}

// ---------------------------------------------------------------------------
// Gather-mean layer 1: wave per node; 2 edges per iter (one per half-wave),
// float4 per lane (wave fetches 1 KB/iter), 3x unrolled -> 6 edges in flight.
// ---------------------------------------------------------------------------
__global__ __launch_bounds__(256) void gather1_kernel(const int* __restrict__ csr_src,
                                                      const int* __restrict__ row_ptr,
                                                      const float* __restrict__ x,
                                                      float* __restrict__ agg1n) {
    int gid = __builtin_amdgcn_readfirstlane(blockIdx.x * 4 + (threadIdx.x >> 6));
    if (gid >= N_NODES) return;
    int lane = threadIdx.x & 63;
    int half = lane >> 5;
    int li = lane & 31;
    int beg = row_ptr[gid], end = row_ptr[gid + 1];
    const float4* x4 = (const float4*)x;
    float4 acc = {0.f, 0.f, 0.f, 0.f};
    int e = beg + half;
    for (; e + 4 < end; e += 6) {
        int s0 = csr_src[e], s1 = csr_src[e + 2], s2 = csr_src[e + 4];
        float4 v0 = x4[(size_t)s0 * 32 + li];
        float4 v1 = x4[(size_t)s1 * 32 + li];
        float4 v2 = x4[(size_t)s2 * 32 + li];
        acc.x += v0.x + v1.x + v2.x;
        acc.y += v0.y + v1.y + v2.y;
        acc.z += v0.z + v1.z + v2.z;
        acc.w += v0.w + v1.w + v2.w;
    }
    for (; e < end; e += 2) {
        int s = csr_src[e];
        float4 v = x4[(size_t)s * 32 + li];
        acc.x += v.x; acc.y += v.y; acc.z += v.z; acc.w += v.w;
    }
    float4 o;
    o.x = __shfl(acc.x, lane ^ 32);
    o.y = __shfl(acc.y, lane ^ 32);
    o.z = __shfl(acc.z, lane ^ 32);
    o.w = __shfl(acc.w, lane ^ 32);
    if (half == 0) {
        float inv = 1.0f / fmaxf((float)(end - beg), 1.0f);
        float4 r;
        r.x = (acc.x + o.x) * inv;
        r.y = (acc.y + o.y) * inv;
        r.z = (acc.z + o.z) * inv;
        r.w = (acc.w + o.w) * inv;
        ((float4*)agg1n)[(size_t)gid * 32 + li] = r;
    }
}

// ---------------------------------------------------------------------------
// GEMM1: h = BN(ReLU(agg1n @ W1l^T + b1 + x @ W1r^T))
// LDS-free: lane = row (A lane-private from global), weights k-major ->
// wave-uniform scalar operand of v_fma. 64 cols/block (acc[64]) halves
// A refetch vs R4 and doubles FMA-per-load. Block = 128 thr (2 waves) ->
// 784 blocks -> ~3 blocks/CU balanced. Grid (391, 2).
// ---------------------------------------------------------------------------
__global__ __launch_bounds__(128) void gemm1_kernel(
    const float* __restrict__ agg1n, const float* __restrict__ x,
    const float* __restrict__ WtA, const float* __restrict__ b1,
    const float* __restrict__ gamma, const float* __restrict__ beta,
    const float* __restrict__ rmean, const float* __restrict__ rvar,
    float* __restrict__ h) {
    const int wid = __builtin_amdgcn_readfirstlane(threadIdx.x >> 6);
    const int lane = threadIdx.x & 63;
    const int row = blockIdx.x * 128 + wid * 64 + lane;
    const int c0 = blockIdx.y * 64;
    const bool valid = row < N_NODES;
    const int rowc = valid ? row : N_NODES - 1;

    float acc[64];
#pragma unroll
    for (int c = 0; c < 64; ++c) acc[c] = 0.f;

#pragma unroll
    for (int phase = 0; phase < 2; ++phase) {
        const float* __restrict__ A = phase ? x : agg1n;
        const float4* __restrict__ Arow = (const float4*)(A + (size_t)rowc * 128);
        const float* __restrict__ Wb = WtA + (size_t)(phase * 128) * 128 + c0;
#pragma unroll 4
        for (int k4 = 0; k4 < 32; ++k4) {
            float4 a4 = Arow[k4];
#pragma unroll
            for (int j = 0; j < 4; ++j) {
                float av = (j == 0) ? a4.x : (j == 1) ? a4.y : (j == 2) ? a4.z : a4.w;
                const float* __restrict__ Wr = Wb + (size_t)(k4 * 4 + j) * 128;
#pragma unroll
                for (int c = 0; c < 64; ++c) acc[c] = fmaf(av, Wr[c], acc[c]);
            }
        }
    }

    if (!valid) return;
    float* hrow = h + (size_t)row * 128 + c0;
#pragma unroll
    for (int q = 0; q < 16; ++q) {
        float rs[4];
#pragma unroll
        for (int u = 0; u < 4; ++u) {
            int c = q * 4 + u;
            float sc = gamma[c0 + c] * rsqrtf(rvar[c0 + c] + BN_EPS);
            float sh = fmaf(-rmean[c0 + c], sc, beta[c0 + c]);
            float pre = acc[c] + b1[c0 + c];
            rs[u] = fmaf(fmaxf(pre, 0.f), sc, sh);
        }
        float4 r = {rs[0], rs[1], rs[2], rs[3]};
        *(float4*)(hrow + q * 4) = r;
    }
}

// ---------------------------------------------------------------------------
// GEMM2: [z2 | p2] = h @ WtB. Single pass over all 80 cols (acc[80]) ->
// h fetched exactly once. cols 0..39 -> z2 (stride 48), 40..79 -> p2
// (stride 40). Grid (391).
// ---------------------------------------------------------------------------
__global__ __launch_bounds__(128) void gemm2_kernel(const float* __restrict__ h,
                                                    const float* __restrict__ WtB,
                                                    float* __restrict__ z2,
                                                    float* __restrict__ p2) {
    const int wid = __builtin_amdgcn_readfirstlane(threadIdx.x >> 6);
    const int lane = threadIdx.x & 63;
    const int row = blockIdx.x * 128 + wid * 64 + lane;
    const bool valid = row < N_NODES;
    const int rowc = valid ? row : N_NODES - 1;

    float acc[80];
#pragma unroll
    for (int c = 0; c < 80; ++c) acc[c] = 0.f;

    const float4* __restrict__ Arow = (const float4*)(h + (size_t)rowc * 128);
#pragma unroll 2
    for (int k4 = 0; k4 < 32; ++k4) {
        float4 a4 = Arow[k4];
#pragma unroll
        for (int j = 0; j < 4; ++j) {
            float av = (j == 0) ? a4.x : (j == 1) ? a4.y : (j == 2) ? a4.z : a4.w;
            const float* __restrict__ Wr = WtB + (size_t)(k4 * 4 + j) * 80;
#pragma unroll
            for (int c = 0; c < 80; ++c) acc[c] = fmaf(av, Wr[c], acc[c]);
        }
    }

    if (!valid) return;
#pragma unroll
    for (int q = 0; q < 10; ++q) {
        float4 r = {acc[q * 4], acc[q * 4 + 1], acc[q * 4 + 2], acc[q * 4 + 3]};
        *(float4*)(z2 + (size_t)row * 48 + q * 4) = r;
    }
#pragma unroll
    for (int q = 0; q < 10; ++q) {
        float4 r = {acc[40 + q * 4], acc[40 + q * 4 + 1], acc[40 + q * 4 + 2],
                    acc[40 + q * 4 + 3]};
        *(float4*)(p2 + (size_t)row * 40 + q * 4) = r;
    }
}

// ---------------------------------------------------------------------------
// Gather layer 2 + final: out = mean_s(z2[s]) + p2[r] + b2
// Wave per node, 5 edges/iter: 12 lanes/edge, float4/lane over stride-48 z2
// rows (cols 40..47 read-and-discarded). Shuffle-reduce; lanes 0..9 write.
// ---------------------------------------------------------------------------
__global__ __launch_bounds__(256) void gather2_kernel(const int* __restrict__ csr_src,
                                                      const int* __restrict__ row_ptr,
                                                      const float* __restrict__ z2,
                                                      const float* __restrict__ p2,
                                                      const float* __restrict__ b2,
                                                      float* __restrict__ out) {
    int gid = __builtin_amdgcn_readfirstlane(blockIdx.x * 4 + (threadIdx.x >> 6));
    if (gid >= N_NODES) return;
    int lane = threadIdx.x & 63;
    int sub = lane / 12;          // 0..5 (5 = inactive)
    int li = lane - sub * 12;     // 0..11
    bool active = sub < 5;
    int beg = row_ptr[gid], end = row_ptr[gid + 1];
    int n = end - beg;
    const float4* z4 = (const float4*)z2;
    float4 acc = {0.f, 0.f, 0.f, 0.f};
    int iters = (n + 4) / 5;
    int e = beg + sub;
    for (int it = 0; it < iters; ++it, e += 5) {
        bool v = active && (e < end);
        int ee = v ? e : beg;
        int s = csr_src[ee];
        float4 t = z4[(size_t)s * 12 + li];
        if (v) {
            acc.x += t.x; acc.y += t.y; acc.z += t.z; acc.w += t.w;
        }
    }
    float4 a0 = acc;
#pragma unroll
    for (int k = 1; k <= 4; ++k) {
        float4 t;
        t.x = __shfl(a0.x, lane + 12 * k);
        t.y = __shfl(a0.y, lane + 12 * k);
        t.z = __shfl(a0.z, lane + 12 * k);
        t.w = __shfl(a0.w, lane + 12 * k);
        acc.x += t.x; acc.y += t.y; acc.z += t.z; acc.w += t.w;
    }
    if (sub == 0 && li < 10) {
        float inv = 1.0f / fmaxf((float)n, 1.0f);
        float4 p = ((const float4*)p2)[(size_t)gid * 10 + li];
        float4 bb = ((const float4*)b2)[li];
        float4 r;
        r.x = fmaf(acc.x, inv, p.x + bb.x);
        r.y = fmaf(acc.y, inv, p.y + bb.y);
        r.z = fmaf(acc.z, inv, p.z + bb.z);
        r.w = fmaf(acc.w, inv, p.w + bb.w);
        ((float4*)out)[(size_t)gid * 10 + li] = r;
    }
}

// ---------------------------------------------------------------------------
// Launch. ws layout:
//   int  deg_i[50048], cursor[50048]          (memset 0 together)
//   int  row_ptr[50052], blk_sum[256], blk_off[256], csr_src[800000]
//   f32  WtA[32768], WtB[10240]
//   f32  agg1n[50048*128]   -- z2[50048*48] + p2[50048*40] alias this region
//   f32  h[50048*128]
// ---------------------------------------------------------------------------
extern "C" void kernel_launch(void* const* d_in, const int* in_sizes, int n_in,
                              void* d_out, int out_size, void* d_ws, size_t ws_size,
                              hipStream_t stream) {
    const float* x     = (const float*)d_in[0];
    const int*   ei    = (const int*)d_in[1];
    const float* W1l   = (const float*)d_in[2];
    const float* b1    = (const float*)d_in[3];
    const float* W1r   = (const float*)d_in[4];
    const float* gamma = (const float*)d_in[5];
    const float* beta  = (const float*)d_in[6];
    const float* rmean = (const float*)d_in[7];
    const float* rvar  = (const float*)d_in[8];
    const float* W2l   = (const float*)d_in[9];
    const float* b2    = (const float*)d_in[10];
    const float* W2r   = (const float*)d_in[11];
    float* out = (float*)d_out;

    int* deg_i   = (int*)d_ws;
    int* cursor  = deg_i + 50048;
    int* row_ptr = cursor + 50048;
    int* blk_sum = row_ptr + 50052;
    int* blk_off = blk_sum + 256;
    int* csr_src = blk_off + 256;
    float* WtA   = (float*)(csr_src + 800000);
    float* WtB   = WtA + 32768;
    float* agg1n = WtB + 10240;
    float* z2    = agg1n;                       // alias (agg1n dead after gemm1)
    float* p2    = z2 + (size_t)50048 * 48;
    float* h     = agg1n + (size_t)50048 * 128;

    const int* src = ei;
    const int* dst = ei + N_EDGES;

    hipMemsetAsync(deg_i, 0, (size_t)(50048 + 50048) * sizeof(int), stream);

    deg_kernel<<<(N_EDGES + 255) / 256, 256, 0, stream>>>(dst, deg_i);
    scanA_kernel<<<SCAN_BLOCKS, 256, 0, stream>>>(deg_i, row_ptr, blk_sum);
    scanB_kernel<<<1, 256, 0, stream>>>(blk_sum, blk_off);
    scanC_kernel<<<SCAN_BLOCKS, 256, 0, stream>>>(row_ptr, blk_off);
    fill_kernel<<<(N_EDGES + 255) / 256, 256, 0, stream>>>(src, dst, row_ptr, cursor, csr_src);

    transposeW_kernel<<<168, 256, 0, stream>>>(W1l, W1r, W2l, W2r, WtA, WtB);

    gather1_kernel<<<(N_NODES + 3) / 4, 256, 0, stream>>>(csr_src, row_ptr, x, agg1n);

    dim3 g1((N_NODES + 127) / 128, 2);
    gemm1_kernel<<<g1, 128, 0, stream>>>(agg1n, x, WtA, b1, gamma, beta, rmean, rvar, h);

    gemm2_kernel<<<(N_NODES + 127) / 128, 128, 0, stream>>>(h, WtB, z2, p2);

    gather2_kernel<<<(N_NODES + 3) / 4, 256, 0, stream>>>(csr_src, row_ptr, z2, p2, b2, out);
}

// Round 6
// 350.892 us; speedup vs baseline: 1.1685x; 1.1685x over previous
//
#include <hip/hip_runtime.h>

#define N_NODES 50000
#define N_EDGES 800000
#define N_FEAT 128
#define N_HID 128
#define N_CLS 40
#define BN_EPS 1e-5f

#define SCAN_BLOCKS ((N_NODES + 255) / 256)  // 196

// ---------------------------------------------------------------------------
// K1: int degree histogram.
// ---------------------------------------------------------------------------
__global__ __launch_bounds__(256) void deg_kernel(const int* __restrict__ dst,
                                                  int* __restrict__ deg_i) {
    int e = blockIdx.x * 256 + threadIdx.x;
    if (e < N_EDGES) atomicAdd(&deg_i[dst[e]], 1);
}

// ---------------------------------------------------------------------------
// Scan A/B/C: row_ptr = exclusive scan of degrees.
// ---------------------------------------------------------------------------
__global__ __launch_bounds__(256) void scanA_kernel(const int* __restrict__ deg_i,
                                                    int* __restrict__ row_ptr,
                                                    int* __restrict__ blk_sum) {
    __shared__ int tmp[256];
    int t = threadIdx.x;
    int i = blockIdx.x * 256 + t;
    int v = (i < N_NODES) ? deg_i[i] : 0;
    tmp[t] = v;
    __syncthreads();
    for (int off = 1; off < 256; off <<= 1) {
        int a = (t >= off) ? tmp[t - off] : 0;
        __syncthreads();
        if (t >= off) tmp[t] += a;
        __syncthreads();
    }
    if (i < N_NODES) row_ptr[i] = tmp[t] - v;
    if (t == 255) blk_sum[blockIdx.x] = tmp[255];
}

__global__ __launch_bounds__(256) void scanB_kernel(const int* __restrict__ blk_sum,
                                                    int* __restrict__ blk_off) {
    __shared__ int tmp[256];
    int t = threadIdx.x;
    int v = (t < SCAN_BLOCKS) ? blk_sum[t] : 0;
    tmp[t] = v;
    __syncthreads();
    for (int off = 1; off < 256; off <<= 1) {
        int a = (t >= off) ? tmp[t - off] : 0;
        __syncthreads();
        if (t >= off) tmp[t] += a;
        __syncthreads();
    }
    if (t < SCAN_BLOCKS) blk_off[t] = tmp[t] - v;
}

__global__ __launch_bounds__(256) void scanC_kernel(int* __restrict__ row_ptr,
                                                    const int* __restrict__ blk_off) {
    int i = blockIdx.x * 256 + threadIdx.x;
    if (i < N_NODES) row_ptr[i] += blk_off[blockIdx.x];
    if (i == 0) row_ptr[N_NODES] = N_EDGES;
}

// ---------------------------------------------------------------------------
// CSR fill.
// ---------------------------------------------------------------------------
__global__ __launch_bounds__(256) void fill_kernel(const int* __restrict__ src,
                                                   const int* __restrict__ dst,
                                                   const int* __restrict__ row_ptr,
                                                   int* __restrict__ cursor,
                                                   int* __restrict__ csr_src) {
    int e = blockIdx.x * 256 + threadIdx.x;
    if (e >= N_EDGES) return;
    int d = dst[e];
    int pos = atomicAdd(&cursor[d], 1);
    csr_src[row_ptr[d] + pos] = src[e];
}

// ---------------------------------------------------------------------------
// Weight transpose to k-major:
//   WtA[k][n] 256x128: k<128 -> W1l[n][k]; else W1r[n][k-128]
//   WtB[k][n] 128x80 : n<40 -> W2l[n][k]; else W2r[n-40][k]
// ---------------------------------------------------------------------------
__global__ __launch_bounds__(256) void transposeW_kernel(
    const float* __restrict__ W1l, const float* __restrict__ W1r,
    const float* __restrict__ W2l, const float* __restrict__ W2r,
    float* __restrict__ WtA, float* __restrict__ WtB) {
    int i = blockIdx.x * 256 + threadIdx.x;
    if (i < 256 * 128) {
        int k = i >> 7, n = i & 127;
        WtA[i] = (k < 128) ? W1l[n * 128 + k] : W1r[n * 128 + (k - 128)];
    } else {
        int j = i - 256 * 128;
        if (j < 128 * 80) {
            int k = j / 80, n = j % 80;
            WtB[j] = (n < 40) ? W2l[n * 128 + k] : W2r[(n - 40) * 128 + k];
        }
    }
}

// ---------------------------------------------------------------------------
// Gather-mean layer 1: wave per node; 2 edges per iter (one per half-wave),
// float4 per lane, 3x unrolled -> 6 edges in flight. Folds inv_deg (mean).
// ---------------------------------------------------------------------------
__global__ __launch_bounds__(256) void gather1_kernel(const int* __restrict__ csr_src,
                                                      const int* __restrict__ row_ptr,
                                                      const float* __restrict__ x,
                                                      float* __restrict__ agg1n) {
    int gid = __builtin_amdgcn_readfirstlane(blockIdx.x * 4 + (threadIdx.x >> 6));
    if (gid >= N_NODES) return;
    int lane = threadIdx.x & 63;
    int half = lane >> 5;
    int li = lane & 31;
    int beg = row_ptr[gid], end = row_ptr[gid + 1];
    const float4* x4 = (const float4*)x;
    float4 acc = {0.f, 0.f, 0.f, 0.f};
    int e = beg + half;
    for (; e + 4 < end; e += 6) {
        int s0 = csr_src[e], s1 = csr_src[e + 2], s2 = csr_src[e + 4];
        float4 v0 = x4[(size_t)s0 * 32 + li];
        float4 v1 = x4[(size_t)s1 * 32 + li];
        float4 v2 = x4[(size_t)s2 * 32 + li];
        acc.x += v0.x + v1.x + v2.x;
        acc.y += v0.y + v1.y + v2.y;
        acc.z += v0.z + v1.z + v2.z;
        acc.w += v0.w + v1.w + v2.w;
    }
    for (; e < end; e += 2) {
        int s = csr_src[e];
        float4 v = x4[(size_t)s * 32 + li];
        acc.x += v.x; acc.y += v.y; acc.z += v.z; acc.w += v.w;
    }
    float4 o;
    o.x = __shfl(acc.x, lane ^ 32);
    o.y = __shfl(acc.y, lane ^ 32);
    o.z = __shfl(acc.z, lane ^ 32);
    o.w = __shfl(acc.w, lane ^ 32);
    if (half == 0) {
        float inv = 1.0f / fmaxf((float)(end - beg), 1.0f);
        float4 r;
        r.x = (acc.x + o.x) * inv;
        r.y = (acc.y + o.y) * inv;
        r.z = (acc.z + o.z) * inv;
        r.w = (acc.w + o.w) * inv;
        ((float4*)agg1n)[(size_t)gid * 32 + li] = r;
    }
}

// ---------------------------------------------------------------------------
// GEMM1: h = BN(ReLU(agg1n @ W1l^T + b1 + x @ W1r^T))
// Block = 64 rows x ALL 128 cols; 4 waves x 32-col slice (acc[32] -- the
// codegen-safe shape). A rows staged ONCE in LDS [64][129] (odd dword
// stride -> even bank spread for staging writes, per-lane b128 reads, and
// epilogue transpose). Weights = wave-uniform scalar loads (no LDS).
// Output routed back through LDS for coalesced h stores.
// A read exactly once: 51.2 MB total. Grid (782).
// ---------------------------------------------------------------------------
__global__ __launch_bounds__(256) void gemm1_kernel(
    const float* __restrict__ agg1n, const float* __restrict__ x,
    const float* __restrict__ WtA, const float* __restrict__ b1,
    const float* __restrict__ gamma, const float* __restrict__ beta,
    const float* __restrict__ rmean, const float* __restrict__ rvar,
    float* __restrict__ h) {
    __shared__ float As[64][129];
    const int t = threadIdx.x;
    const int wid = __builtin_amdgcn_readfirstlane(t >> 6);
    const int lane = t & 63;
    const int mbase = blockIdx.x * 64;
    const int c0 = wid * 32;

    float acc[32];
#pragma unroll
    for (int c = 0; c < 32; ++c) acc[c] = 0.f;

    for (int phase = 0; phase < 2; ++phase) {
        const float* __restrict__ A = phase ? x : agg1n;
        __syncthreads();  // previous phase's readers done before overwrite
        // stage 64 rows x 128 floats (coalesced global, even-bank ds_write)
#pragma unroll
        for (int i = 0; i < 8; ++i) {
            int e = i * 256 + t;
            int r = e >> 5, k4 = e & 31;
            int rr = mbase + r;
            rr = (rr < N_NODES) ? rr : N_NODES - 1;
            float4 v = ((const float4*)A)[(size_t)rr * 32 + k4];
            *(float4*)&As[r][k4 * 4] = v;
        }
        __syncthreads();
        const float* __restrict__ Wp = WtA + (size_t)(phase << 7) * 128 + c0;
#pragma unroll 4
        for (int k4 = 0; k4 < 32; ++k4) {
            float4 a4 = *(const float4*)&As[lane][k4 * 4];
#pragma unroll
            for (int j = 0; j < 4; ++j) {
                float av = (j == 0) ? a4.x : (j == 1) ? a4.y : (j == 2) ? a4.z : a4.w;
                const float* __restrict__ Wr = Wp + (size_t)(k4 * 4 + j) * 128;
#pragma unroll
                for (int c = 0; c < 32; ++c) acc[c] = fmaf(av, Wr[c], acc[c]);
            }
        }
    }

    // epilogue: bias + ReLU + BN, write back to LDS (row=lane, cols c0..c0+31)
    __syncthreads();  // all compute reads done; As becomes output buffer
#pragma unroll
    for (int q = 0; q < 8; ++q) {
        float rs[4];
#pragma unroll
        for (int u = 0; u < 4; ++u) {
            int c = q * 4 + u;
            float sc = gamma[c0 + c] * rsqrtf(rvar[c0 + c] + BN_EPS);
            float sh = fmaf(-rmean[c0 + c], sc, beta[c0 + c]);
            float pre = acc[c] + b1[c0 + c];
            rs[u] = fmaf(fmaxf(pre, 0.f), sc, sh);
        }
        float4 r = {rs[0], rs[1], rs[2], rs[3]};
        *(float4*)&As[lane][c0 + q * 4] = r;
    }
    __syncthreads();
    // coalesced copy-out
#pragma unroll
    for (int i = 0; i < 8; ++i) {
        int e = i * 256 + t;
        int r = e >> 5, k4 = e & 31;
        if (mbase + r < N_NODES) {
            float4 v = *(const float4*)&As[r][k4 * 4];
            ((float4*)h)[(size_t)(mbase + r) * 32 + k4] = v;
        }
    }
}

// ---------------------------------------------------------------------------
// GEMM2: [z2 | p2] = h @ WtB. Same structure: 64 rows x 80 cols, 4 waves x
// 20 cols (acc[20]), h staged once in LDS, outputs copied out coalesced via
// LDS. z2 stride 48 (pad cols hold garbage -- gather2 discards), p2 stride 40.
// ---------------------------------------------------------------------------
__global__ __launch_bounds__(256) void gemm2_kernel(const float* __restrict__ h,
                                                    const float* __restrict__ WtB,
                                                    float* __restrict__ z2,
                                                    float* __restrict__ p2) {
    __shared__ float As[64][129];
    const int t = threadIdx.x;
    const int wid = __builtin_amdgcn_readfirstlane(t >> 6);
    const int lane = t & 63;
    const int mbase = blockIdx.x * 64;
    const int c0 = wid * 20;

    float acc[20];
#pragma unroll
    for (int c = 0; c < 20; ++c) acc[c] = 0.f;

#pragma unroll
    for (int i = 0; i < 8; ++i) {
        int e = i * 256 + t;
        int r = e >> 5, k4 = e & 31;
        int rr = mbase + r;
        rr = (rr < N_NODES) ? rr : N_NODES - 1;
        float4 v = ((const float4*)h)[(size_t)rr * 32 + k4];
        *(float4*)&As[r][k4 * 4] = v;
    }
    __syncthreads();
#pragma unroll 4
    for (int k4 = 0; k4 < 32; ++k4) {
        float4 a4 = *(const float4*)&As[lane][k4 * 4];
#pragma unroll
        for (int j = 0; j < 4; ++j) {
            float av = (j == 0) ? a4.x : (j == 1) ? a4.y : (j == 2) ? a4.z : a4.w;
            const float* __restrict__ Wr = WtB + (size_t)(k4 * 4 + j) * 80 + c0;
#pragma unroll
            for (int c = 0; c < 20; ++c) acc[c] = fmaf(av, Wr[c], acc[c]);
        }
    }

    __syncthreads();
#pragma unroll
    for (int c = 0; c < 20; ++c) As[lane][c0 + c] = acc[c];
    __syncthreads();

    // z2: 64 rows x 12 float4 (cols 0..47; 40..47 garbage, discarded later)
#pragma unroll
    for (int i = 0; i < 3; ++i) {
        int e = i * 256 + t;  // < 768
        int r = e / 12, q = e - r * 12;
        if (mbase + r < N_NODES) {
            float4 v = *(const float4*)&As[r][q * 4];
            *(float4*)(z2 + (size_t)(mbase + r) * 48 + q * 4) = v;
        }
    }
    // p2: 64 rows x 10 float4 (cols 40..79)
    for (int e = t; e < 640; e += 256) {
        int r = e / 10, q = e - r * 10;
        if (mbase + r < N_NODES) {
            float4 v = *(const float4*)&As[r][40 + q * 4];
            *(float4*)(p2 + (size_t)(mbase + r) * 40 + q * 4) = v;
        }
    }
}

// ---------------------------------------------------------------------------
// Gather layer 2 + final: out = mean_s(z2[s]) + p2[r] + b2
// Wave per node, 5 edges/iter: 12 lanes/edge, float4/lane over stride-48 z2
// rows (cols 40..47 read-and-discarded). Shuffle-reduce; lanes 0..9 write.
// ---------------------------------------------------------------------------
__global__ __launch_bounds__(256) void gather2_kernel(const int* __restrict__ csr_src,
                                                      const int* __restrict__ row_ptr,
                                                      const float* __restrict__ z2,
                                                      const float* __restrict__ p2,
                                                      const float* __restrict__ b2,
                                                      float* __restrict__ out) {
    int gid = __builtin_amdgcn_readfirstlane(blockIdx.x * 4 + (threadIdx.x >> 6));
    if (gid >= N_NODES) return;
    int lane = threadIdx.x & 63;
    int sub = lane / 12;          // 0..5 (5 = inactive)
    int li = lane - sub * 12;     // 0..11
    bool active = sub < 5;
    int beg = row_ptr[gid], end = row_ptr[gid + 1];
    int n = end - beg;
    const float4* z4 = (const float4*)z2;
    float4 acc = {0.f, 0.f, 0.f, 0.f};
    int iters = (n + 4) / 5;
    int e = beg + sub;
    for (int it = 0; it < iters; ++it, e += 5) {
        bool v = active && (e < end);
        int ee = v ? e : beg;
        int s = csr_src[ee];
        float4 t = z4[(size_t)s * 12 + li];
        if (v) {
            acc.x += t.x; acc.y += t.y; acc.z += t.z; acc.w += t.w;
        }
    }
    float4 a0 = acc;
#pragma unroll
    for (int k = 1; k <= 4; ++k) {
        float4 t;
        t.x = __shfl(a0.x, lane + 12 * k);
        t.y = __shfl(a0.y, lane + 12 * k);
        t.z = __shfl(a0.z, lane + 12 * k);
        t.w = __shfl(a0.w, lane + 12 * k);
        acc.x += t.x; acc.y += t.y; acc.z += t.z; acc.w += t.w;
    }
    if (sub == 0 && li < 10) {
        float inv = 1.0f / fmaxf((float)n, 1.0f);
        float4 p = ((const float4*)p2)[(size_t)gid * 10 + li];
        float4 bb = ((const float4*)b2)[li];
        float4 r;
        r.x = fmaf(acc.x, inv, p.x + bb.x);
        r.y = fmaf(acc.y, inv, p.y + bb.y);
        r.z = fmaf(acc.z, inv, p.z + bb.z);
        r.w = fmaf(acc.w, inv, p.w + bb.w);
        ((float4*)out)[(size_t)gid * 10 + li] = r;
    }
}

// ---------------------------------------------------------------------------
// Launch. ws layout:
//   int  deg_i[50048], cursor[50048]          (memset 0 together)
//   int  row_ptr[50052], blk_sum[256], blk_off[256], csr_src[800000]
//   f32  WtA[32768], WtB[10240]
//   f32  agg1n[50048*128]   -- z2[50048*48] + p2[50048*40] alias this region
//   f32  h[50048*128]
// ---------------------------------------------------------------------------
extern "C" void kernel_launch(void* const* d_in, const int* in_sizes, int n_in,
                              void* d_out, int out_size, void* d_ws, size_t ws_size,
                              hipStream_t stream) {
    const float* x     = (const float*)d_in[0];
    const int*   ei    = (const int*)d_in[1];
    const float* W1l   = (const float*)d_in[2];
    const float* b1    = (const float*)d_in[3];
    const float* W1r   = (const float*)d_in[4];
    const float* gamma = (const float*)d_in[5];
    const float* beta  = (const float*)d_in[6];
    const float* rmean = (const float*)d_in[7];
    const float* rvar  = (const float*)d_in[8];
    const float* W2l   = (const float*)d_in[9];
    const float* b2    = (const float*)d_in[10];
    const float* W2r   = (const float*)d_in[11];
    float* out = (float*)d_out;

    int* deg_i   = (int*)d_ws;
    int* cursor  = deg_i + 50048;
    int* row_ptr = cursor + 50048;
    int* blk_sum = row_ptr + 50052;
    int* blk_off = blk_sum + 256;
    int* csr_src = blk_off + 256;
    float* WtA   = (float*)(csr_src + 800000);
    float* WtB   = WtA + 32768;
    float* agg1n = WtB + 10240;
    float* z2    = agg1n;                       // alias (agg1n dead after gemm1)
    float* p2    = z2 + (size_t)50048 * 48;
    float* h     = agg1n + (size_t)50048 * 128;

    const int* src = ei;
    const int* dst = ei + N_EDGES;

    hipMemsetAsync(deg_i, 0, (size_t)(50048 + 50048) * sizeof(int), stream);

    deg_kernel<<<(N_EDGES + 255) / 256, 256, 0, stream>>>(dst, deg_i);
    scanA_kernel<<<SCAN_BLOCKS, 256, 0, stream>>>(deg_i, row_ptr, blk_sum);
    scanB_kernel<<<1, 256, 0, stream>>>(blk_sum, blk_off);
    scanC_kernel<<<SCAN_BLOCKS, 256, 0, stream>>>(row_ptr, blk_off);
    fill_kernel<<<(N_EDGES + 255) / 256, 256, 0, stream>>>(src, dst, row_ptr, cursor, csr_src);

    transposeW_kernel<<<168, 256, 0, stream>>>(W1l, W1r, W2l, W2r, WtA, WtB);

    gather1_kernel<<<(N_NODES + 3) / 4, 256, 0, stream>>>(csr_src, row_ptr, x, agg1n);

    gemm1_kernel<<<(N_NODES + 63) / 64, 256, 0, stream>>>(agg1n, x, WtA, b1, gamma,
                                                          beta, rmean, rvar, h);

    gemm2_kernel<<<(N_NODES + 63) / 64, 256, 0, stream>>>(h, WtB, z2, p2);

    gather2_kernel<<<(N_NODES + 3) / 4, 256, 0, stream>>>(csr_src, row_ptr, z2, p2, b2, out);
}